// Round 10
// baseline (96.030 us; speedup 1.0000x reference)
//
#include <hip/hip_runtime.h>

// SqueezeSeg recurrent CRF, MI355X (gfx950). Single-kernel halo-redundant fusion,
// 3 CRF iterations per block over nested shrinking regions (12x72 -> 10x68 ->
// 8x64 around the owned 8x64 tile). 512-thread blocks (2 blocks/CU), XCD-aware
// block swizzle (r9, -2us), ping-pong u_lds (r8), persist-fold fm=f*m (r6).
// NEW: straight-line phase 0 with CORRECT-ORDER filt prefetch —
//   issue x/mask loads (oldest) -> issue filt burst -> consume x (vmcnt can
//   retire x while the 14 newer filt loads stay in flight; vmcnt decrements in
//   issue order, which is why r4's filt-FIRST order anti-overlapped) ->
//   softmax + LDS stores + barrier hide the filt HBM latency.
// g_ang == g_bi (theta=0.9 both) -> ang == bi_ang.
// compat = (1-I)*coef -> out[o] = coef*(sum_c v[c] - v[o]).

#define NCLASS 4
#define HH 64
#define WW 512
#define BB 16
#define TH 8
#define TW 64
#define UR (TH + 6)     // 14 rows:  tile + 3 halo each side
#define UC (TW + 12)    // 76 cols:  tile + 6 halo each side
#define HUC (UC / 2)    // 38 pairs per patch row
#define PLANE (HH * WW)
#define R1H 12          // step-1 region rows
#define R1W 72          // step-1 region cols
#define GPR1 (R1W / 2)  // 36 pixel-pairs per region row
#define NPAIR1 (R1H * GPR1)  // 432 pairs, one per thread
#define NXCD 8
#define NBLK (WW / TW * HH / TH * BB)   // 1024, divisible by NXCD

// exp(-d2 / (2*0.9^2)) for d2 = 1,2,4,5
#define G1 0.53940412f
#define G2 0.29095687f
#define G4 0.08466190f
#define G5 0.04566227f

__device__ __forceinline__ void fma4(float4& d, float s, const float4& v) {
    d.x = fmaf(s, v.x, d.x);
    d.y = fmaf(s, v.y, d.y);
    d.z = fmaf(s, v.z, d.z);
    d.w = fmaf(s, v.w, d.w);
}

// softmax over the class dim for a pixel PAIR held in 4 float2 registers
__device__ __forceinline__ void softmax_pair(const float2 v0, const float2 v1,
                                             const float2 v2, const float2 v3,
                                             float4& u0, float4& u1)
{
    {
        const float mx  = fmaxf(fmaxf(v0.x, v1.x), fmaxf(v2.x, v3.x));
        const float e0  = __expf(v0.x - mx);
        const float e1  = __expf(v1.x - mx);
        const float e2  = __expf(v2.x - mx);
        const float e3  = __expf(v3.x - mx);
        const float inv = 1.0f / (e0 + e1 + e2 + e3);
        u0 = make_float4(e0 * inv, e1 * inv, e2 * inv, e3 * inv);
    }
    {
        const float mx  = fmaxf(fmaxf(v0.y, v1.y), fmaxf(v2.y, v3.y));
        const float e0  = __expf(v0.y - mx);
        const float e1  = __expf(v1.y - mx);
        const float e2  = __expf(v2.y - mx);
        const float e3  = __expf(v3.y - mx);
        const float inv = 1.0f / (e0 + e1 + e2 + e3);
        u1 = make_float4(e0 * inv, e1 * inv, e2 * inv, e3 * inv);
    }
}

// combine ang/bilateral accumulators into the new x (optionally softmaxed)
template <bool SM>
__device__ __forceinline__ float4 crf_combine(const float4 A, const float4 C,
                                              const float4 u, const float mcen)
{
    const float bx = C.x * mcen * A.x;
    const float by = C.y * mcen * A.y;
    const float bz = C.z * mcen * A.z;
    const float bw = C.w * mcen * A.w;
    const float sa = A.x + A.y + A.z + A.w;
    const float sb = bx + by + bz + bw;
    float4 r;
    r.x = u.x + 0.02f * (sa - A.x) + 0.1f * (sb - bx);
    r.y = u.y + 0.02f * (sa - A.y) + 0.1f * (sb - by);
    r.z = u.z + 0.02f * (sa - A.z) + 0.1f * (sb - bz);
    r.w = u.w + 0.02f * (sa - A.w) + 0.1f * (sb - bw);
    if (SM) {
        const float mx  = fmaxf(fmaxf(r.x, r.y), fmaxf(r.z, r.w));
        const float e0  = __expf(r.x - mx);
        const float e1  = __expf(r.y - mx);
        const float e2  = __expf(r.z - mx);
        const float e3  = __expf(r.w - mx);
        const float inv = 1.0f / (e0 + e1 + e2 + e3);
        r = make_float4(e0 * inv, e1 * inv, e2 * inv, e3 * inv);
    }
    return r;
}

// One CRF step for this thread's FIXED pixel pair. Reads u_src, writes u_dst
// (ping-pong) or global (FINAL).
// FIRST: fm[] holds raw filt taps; read mask from LDS, compute fm=f*m inline
//        and PERSIST the products + mcen. !FIRST: fm[] holds folded products.
template <int MR, int MC, bool FIRST, bool FINAL>
__device__ __forceinline__ void crf_step(
    const float4 (*__restrict__ u_src)[UC], float4 (*__restrict__ u_dst)[UC],
    const float (*__restrict__ m_lds)[UC],
    float2* __restrict__ fm, float& mcen0, float& mcen1,
    float* __restrict__ dst,
    int b, int lr1, int lc1, int gh, int gw, bool valid, bool inb)
{
    constexpr int RH = TH + 2 * MR;
    constexpr int RW = TW + 2 * MC;
    // this step's region, expressed in step-1 coordinates (nested subsets)
    constexpr int LR_LO = 2 - MR, LR_HI = 2 - MR + RH;
    constexpr int LC_LO = 4 - MC, LC_HI = 4 - MC + RW;

    // in_region: p-based (writes r=0 for global-OOB cells -> zero-pad kept)
    const bool in_region = valid && lr1 >= LR_LO && lr1 < LR_HI
                                 && lc1 >= LC_LO && (lc1 + 1) < LC_HI;
    const bool act = in_region && inb;

    // Gaussian weights per tap column (t = da+2); edge rows vs center row
    const float GE[5] = {G5, G2, G1, G2, G5};
    const float GC[5] = {G4, G1, 0.f, G1, G4};

    float4 r0 = make_float4(0.f, 0.f, 0.f, 0.f);
    float4 r1 = r0;

    if (act) {
        const int ur = lr1 + 1;   // u row of this pair
        const int uc = lc1 + 2;   // u col of first pixel (even)

        float4 A0 = make_float4(0.f, 0.f, 0.f, 0.f);
        float4 A1 = A0, C0 = A0, C1 = A0;
        float4 ucen0 = A0, ucen1 = A0;

#pragma unroll
        for (int dz = -1; dz <= 1; ++dz) {
            const int rr = ur + dz;
            // 6-wide shared window: cols uc-2 .. uc+3 (uc even -> aligned)
            float4 U[6];
            float  M[6];
#pragma unroll
            for (int t = 0; t < 6; ++t) U[t] = u_src[rr][uc - 2 + t];
            if (FIRST) {
#pragma unroll
                for (int t = 0; t < 3; ++t) {
                    const float2 mm =
                        *reinterpret_cast<const float2*>(&m_lds[rr][uc - 2 + 2 * t]);
                    M[2 * t]     = mm.x;
                    M[2 * t + 1] = mm.y;
                }
            }
            if (dz == 0) {
                ucen0 = U[2]; ucen1 = U[3];
                if (FIRST) { mcen0 = M[2]; mcen1 = M[3]; }
            }
#pragma unroll
            for (int t = 0; t < 5; ++t) {
                if (dz == 0 && t == 2) continue;   // center excluded
                const int   k  = (dz == -1) ? t
                               : (dz == 0)  ? 5 + (t > 2 ? t - 1 : t)
                                            : 9 + t;
                const float gk = (dz == 0) ? GC[t] : GE[t];
                float fm0, fm1;
                if (FIRST) {
                    fm0 = fm[k].x * M[t];
                    fm1 = fm[k].y * M[t + 1];
                    fm[k].x = fm0;           // persist folded product
                    fm[k].y = fm1;
                } else {
                    fm0 = fm[k].x;
                    fm1 = fm[k].y;
                }
                fma4(A0, gk,  U[t]);      fma4(C0, fm0, U[t]);
                fma4(A1, gk,  U[t + 1]);  fma4(C1, fm1, U[t + 1]);
            }
        }
        r0 = crf_combine<!FINAL>(A0, C0, ucen0, mcen0);
        r1 = crf_combine<!FINAL>(A1, C1, ucen1, mcen1);

        if (FINAL) {
            float* o = dst + ((size_t)b * NCLASS * HH + gh) * WW + gw;
            *reinterpret_cast<float2*>(o)             = make_float2(r0.x, r1.x);
            *reinterpret_cast<float2*>(o + PLANE)     = make_float2(r0.y, r1.y);
            *reinterpret_cast<float2*>(o + 2 * PLANE) = make_float2(r0.z, r1.z);
            *reinterpret_cast<float2*>(o + 3 * PLANE) = make_float2(r0.w, r1.w);
        }
    }

    if (!FINAL) {
        if (in_region) {
            u_dst[lr1 + 1][lc1 + 2] = r0;    // r=0 where global-OOB (zero-pad)
            u_dst[lr1 + 1][lc1 + 3] = r1;
        }
        __syncthreads();   // dst writes visible; src free for reuse next step
    }
}

__global__ __launch_bounds__(512, 4) void crf_fused(
    const float* __restrict__ xin,   // [B,4,H,W]
    const float* __restrict__ filt,  // [B,1,14,H,W]
    const float* __restrict__ mask,  // [B,1,H,W]
    float* __restrict__ xout)        // [B,4,H,W]
{
    __shared__ float4 u0_lds[UR][UC];  // unary ping, 17.0 KB
    __shared__ float4 u1_lds[UR][UC];  // unary pong, 17.0 KB
    __shared__ float  m_lds[UR][UC];   // mask, 4.3 KB

    // ---- XCD-aware swizzle: each XCD gets 128 CONSECUTIVE tile-ids (=2 whole
    // batch images) so halo-sharing neighbor tiles co-reside on one L2.
    const int bid  = blockIdx.x;                    // 0..1023
    const int xcd  = bid % NXCD;
    const int tile = xcd * (NBLK / NXCD) + bid / NXCD;   // bijective (1024%8==0)
    const int wx   = tile & 7;          // tile % (WW/TW)
    const int hy   = (tile >> 3) & 7;   // (tile/8) % (HH/TH)
    const int b    = tile >> 6;         // tile / 64

    const int h0  = hy * TH;
    const int w0  = wx * TW;
    const int tid = threadIdx.x;

    // ---- fixed thread -> pixel-pair mapping over the step-1 region ----
    const int  p     = tid;                    // pair id (0..431 active)
    const int  lr1   = p / GPR1;               // region row
    const int  lc1   = 2 * (p - lr1 * GPR1);   // region col of first pixel (even)
    const int  gh    = h0 + lr1 - 2;
    const int  gw    = w0 + lc1 - 4;
    const bool valid = (p < NPAIR1);
    const bool inb   = valid && gh >= 0 && gh < HH && gw >= 0 && gw < WW;

    // ---- phase 0 (straight-line): main pair = tid, tail pairs 512..531 on
    // threads 0..19. Order: x/mask loads FIRST, then the filt burst, THEN
    // softmax consumption -> x retires via counted vmcnt while filt stays in
    // flight; filt latency hides under softmax + LDS stores + barrier.
    const int  mlr  = tid / HUC;
    const int  mlc  = 2 * (tid - mlr * HUC);
    const int  mph  = h0 + mlr - 3;
    const int  mpw  = w0 + mlc - 6;            // even -> never straddles 0/W
    const bool minb = mph >= 0 && mph < HH && mpw >= 0 && mpw < WW;

    const bool tact = tid < (UR * UC) / 2 - 512;   // 20 tail pairs
    const int  tlr  = 13;                           // all tail pairs on row 13
    const int  tlc  = 2 * (18 + tid);
    const int  tph  = h0 + tlr - 3;
    const int  tpw  = w0 + tlc - 6;
    const bool tinb = tact && tph >= 0 && tph < HH && tpw >= 0 && tpw < WW;

    float2 mv0, mv1, mv2, mv3, mmm;            // main pair x + mask
    mv0 = mv1 = mv2 = mv3 = mmm = make_float2(0.f, 0.f);
    if (minb) {
        const float* px = xin + ((size_t)b * NCLASS * HH + mph) * WW + mpw;
        mv0 = *reinterpret_cast<const float2*>(px);
        mv1 = *reinterpret_cast<const float2*>(px + PLANE);
        mv2 = *reinterpret_cast<const float2*>(px + 2 * PLANE);
        mv3 = *reinterpret_cast<const float2*>(px + 3 * PLANE);
        mmm = *reinterpret_cast<const float2*>(mask + ((size_t)b * HH + mph) * WW + mpw);
    }
    float2 tv0, tv1, tv2, tv3, tmm;            // tail pair x + mask
    tv0 = tv1 = tv2 = tv3 = tmm = make_float2(0.f, 0.f);
    if (tinb) {
        const float* px = xin + ((size_t)b * NCLASS * HH + tph) * WW + tpw;
        tv0 = *reinterpret_cast<const float2*>(px);
        tv1 = *reinterpret_cast<const float2*>(px + PLANE);
        tv2 = *reinterpret_cast<const float2*>(px + 2 * PLANE);
        tv3 = *reinterpret_cast<const float2*>(px + 3 * PLANE);
        tmm = *reinterpret_cast<const float2*>(mask + ((size_t)b * HH + tph) * WW + tpw);
    }

    // ---- filt burst: issued AFTER x/mask, BEFORE softmax consumption ----
    float2 f[14];
    if (inb) {
        const float* fp = filt + ((size_t)b * 14 * HH + gh) * WW + gw;
#pragma unroll
        for (int k = 0; k < 14; ++k)
            f[k] = *reinterpret_cast<const float2*>(fp + (size_t)k * PLANE);
    }

    // ---- softmax + LDS stores (x retires here; filt still in flight) ----
    {
        float4 u0, u1;
        softmax_pair(mv0, mv1, mv2, mv3, u0, u1);
        if (!minb) { u0 = make_float4(0.f, 0.f, 0.f, 0.f); u1 = u0; }
        u0_lds[mlr][mlc]     = u0;
        u0_lds[mlr][mlc + 1] = u1;
        *reinterpret_cast<float2*>(&m_lds[mlr][mlc]) = mmm;
    }
    if (tact) {
        float4 u0, u1;
        softmax_pair(tv0, tv1, tv2, tv3, u0, u1);
        if (!tinb) { u0 = make_float4(0.f, 0.f, 0.f, 0.f); u1 = u0; }
        u0_lds[tlr][tlc]     = u0;
        u0_lds[tlr][tlc + 1] = u1;
        *reinterpret_cast<float2*>(&m_lds[tlr][tlc]) = tmm;
    }
    __syncthreads();

    float mcen0 = 0.f, mcen1 = 0.f;
    crf_step<2, 4, true,  false>(u0_lds, u1_lds, m_lds, f, mcen0, mcen1, xout,
                                 b, lr1, lc1, gh, gw, valid, inb);
    crf_step<1, 2, false, false>(u1_lds, u0_lds, m_lds, f, mcen0, mcen1, xout,
                                 b, lr1, lc1, gh, gw, valid, inb);
    crf_step<0, 0, false, true >(u0_lds, u1_lds, m_lds, f, mcen0, mcen1, xout,
                                 b, lr1, lc1, gh, gw, valid, inb);
}

extern "C" void kernel_launch(void* const* d_in, const int* in_sizes, int n_in,
                              void* d_out, int out_size, void* d_ws, size_t ws_size,
                              hipStream_t stream) {
    const float* x    = (const float*)d_in[0];  // [16,4,64,512]
    const float* filt = (const float*)d_in[1];  // [16,1,14,64,512]
    const float* msk  = (const float*)d_in[2];  // [16,1,64,512]
    float* out = (float*)d_out;
    (void)d_ws; (void)ws_size;

    dim3 grid(NBLK);   // 1024 blocks, 1D; tile decomposition + XCD swizzle in-kernel
    dim3 block(512);
    crf_fused<<<grid, block, 0, stream>>>(x, filt, msk, out);
}

// Round 11
// 93.937 us; speedup vs baseline: 1.0223x; 1.0223x over previous
//
#include <hip/hip_runtime.h>

// SqueezeSeg recurrent CRF, MI355X (gfx950). Single-kernel halo-redundant fusion,
// 3 CRF iterations per block over nested shrinking regions (12x72 -> 10x68 ->
// 8x64 around the owned 8x64 tile). Fixed thread->pixel-pair mapping, 512-thread
// blocks (8 waves, ~110 VGPR -> 2 blocks/CU; r7: 1024-thread blocks = 1 block/CU
// regressed). Ping-pong u_lds (r8, 3 barriers). XCD-aware block swizzle (r9):
// 1024 blocks / 8 XCDs = 128 consecutive tile-ids per XCD = 2 whole batch
// images, so the ~64 concurrently-resident blocks of an XCD cover ONE image and
// all halo-sharing neighbor tiles hit the same 4MB L2.
// == This is the r9 kernel (94.1us, session best), reverted after r10's
//    ordered-prefetch phase 0 regressed (+1.9us). Do NOT re-attempt source-level
//    filt prefetch: both orderings (r4 filt-first +10us, r10 x-first +1.9us)
//    lose — hipcc's waitcnt placement across the divergent filt block defeats
//    the intended counted-vmcnt overlap. ==
// Proven-schedule invariants:
//  - filt loads post-barrier; step-1 A-side overlaps the in-flight burst.
//  - fm = f*mask folded inline in step 1, persisted in f regs; steps 2-3 have
//    no mask reads / no muls.
//  - in_region writes r=0 for global-OOB cells -> zero-pad semantics hold.
// g_ang == g_bi (theta=0.9 both) -> ang == bi_ang.
// compat = (1-I)*coef -> out[o] = coef*(sum_c v[c] - v[o]).

#define NCLASS 4
#define HH 64
#define WW 512
#define BB 16
#define TH 8
#define TW 64
#define UR (TH + 6)     // 14 rows:  tile + 3 halo each side
#define UC (TW + 12)    // 76 cols:  tile + 6 halo each side
#define PLANE (HH * WW)
#define R1H 12          // step-1 region rows
#define R1W 72          // step-1 region cols
#define GPR1 (R1W / 2)  // 36 pixel-pairs per region row
#define NPAIR1 (R1H * GPR1)  // 432 pairs, one per thread
#define NXCD 8
#define NBLK (WW / TW * HH / TH * BB)   // 1024, divisible by NXCD

// exp(-d2 / (2*0.9^2)) for d2 = 1,2,4,5
#define G1 0.53940412f
#define G2 0.29095687f
#define G4 0.08466190f
#define G5 0.04566227f

__device__ __forceinline__ void fma4(float4& d, float s, const float4& v) {
    d.x = fmaf(s, v.x, d.x);
    d.y = fmaf(s, v.y, d.y);
    d.z = fmaf(s, v.z, d.z);
    d.w = fmaf(s, v.w, d.w);
}

// combine ang/bilateral accumulators into the new x (optionally softmaxed)
template <bool SM>
__device__ __forceinline__ float4 crf_combine(const float4 A, const float4 C,
                                              const float4 u, const float mcen)
{
    const float bx = C.x * mcen * A.x;
    const float by = C.y * mcen * A.y;
    const float bz = C.z * mcen * A.z;
    const float bw = C.w * mcen * A.w;
    const float sa = A.x + A.y + A.z + A.w;
    const float sb = bx + by + bz + bw;
    float4 r;
    r.x = u.x + 0.02f * (sa - A.x) + 0.1f * (sb - bx);
    r.y = u.y + 0.02f * (sa - A.y) + 0.1f * (sb - by);
    r.z = u.z + 0.02f * (sa - A.z) + 0.1f * (sb - bz);
    r.w = u.w + 0.02f * (sa - A.w) + 0.1f * (sb - bw);
    if (SM) {
        const float mx  = fmaxf(fmaxf(r.x, r.y), fmaxf(r.z, r.w));
        const float e0  = __expf(r.x - mx);
        const float e1  = __expf(r.y - mx);
        const float e2  = __expf(r.z - mx);
        const float e3  = __expf(r.w - mx);
        const float inv = 1.0f / (e0 + e1 + e2 + e3);
        r = make_float4(e0 * inv, e1 * inv, e2 * inv, e3 * inv);
    }
    return r;
}

// One CRF step for this thread's FIXED pixel pair. Reads u_src, writes u_dst
// (ping-pong) or global (FINAL).
// FIRST: fm[] holds raw filt taps; read mask from LDS, compute fm=f*m inline
//        and PERSIST the products + mcen. !FIRST: fm[] holds folded products.
template <int MR, int MC, bool FIRST, bool FINAL>
__device__ __forceinline__ void crf_step(
    const float4 (*__restrict__ u_src)[UC], float4 (*__restrict__ u_dst)[UC],
    const float (*__restrict__ m_lds)[UC],
    float2* __restrict__ fm, float& mcen0, float& mcen1,
    float* __restrict__ dst,
    int b, int lr1, int lc1, int gh, int gw, bool valid, bool inb)
{
    constexpr int RH = TH + 2 * MR;
    constexpr int RW = TW + 2 * MC;
    // this step's region, expressed in step-1 coordinates (nested subsets)
    constexpr int LR_LO = 2 - MR, LR_HI = 2 - MR + RH;
    constexpr int LC_LO = 4 - MC, LC_HI = 4 - MC + RW;

    // in_region: p-based (writes r=0 for global-OOB cells -> zero-pad kept)
    const bool in_region = valid && lr1 >= LR_LO && lr1 < LR_HI
                                 && lc1 >= LC_LO && (lc1 + 1) < LC_HI;
    const bool act = in_region && inb;

    // Gaussian weights per tap column (t = da+2); edge rows vs center row
    const float GE[5] = {G5, G2, G1, G2, G5};
    const float GC[5] = {G4, G1, 0.f, G1, G4};

    float4 r0 = make_float4(0.f, 0.f, 0.f, 0.f);
    float4 r1 = r0;

    if (act) {
        const int ur = lr1 + 1;   // u row of this pair
        const int uc = lc1 + 2;   // u col of first pixel (even)

        float4 A0 = make_float4(0.f, 0.f, 0.f, 0.f);
        float4 A1 = A0, C0 = A0, C1 = A0;
        float4 ucen0 = A0, ucen1 = A0;

#pragma unroll
        for (int dz = -1; dz <= 1; ++dz) {
            const int rr = ur + dz;
            // 6-wide shared window: cols uc-2 .. uc+3 (uc even -> aligned)
            float4 U[6];
            float  M[6];
#pragma unroll
            for (int t = 0; t < 6; ++t) U[t] = u_src[rr][uc - 2 + t];
            if (FIRST) {
#pragma unroll
                for (int t = 0; t < 3; ++t) {
                    const float2 mm =
                        *reinterpret_cast<const float2*>(&m_lds[rr][uc - 2 + 2 * t]);
                    M[2 * t]     = mm.x;
                    M[2 * t + 1] = mm.y;
                }
            }
            if (dz == 0) {
                ucen0 = U[2]; ucen1 = U[3];
                if (FIRST) { mcen0 = M[2]; mcen1 = M[3]; }
            }
#pragma unroll
            for (int t = 0; t < 5; ++t) {
                if (dz == 0 && t == 2) continue;   // center excluded
                const int   k  = (dz == -1) ? t
                               : (dz == 0)  ? 5 + (t > 2 ? t - 1 : t)
                                            : 9 + t;
                const float gk = (dz == 0) ? GC[t] : GE[t];
                float fm0, fm1;
                if (FIRST) {
                    fm0 = fm[k].x * M[t];
                    fm1 = fm[k].y * M[t + 1];
                    fm[k].x = fm0;           // persist folded product
                    fm[k].y = fm1;
                } else {
                    fm0 = fm[k].x;
                    fm1 = fm[k].y;
                }
                fma4(A0, gk,  U[t]);      fma4(C0, fm0, U[t]);
                fma4(A1, gk,  U[t + 1]);  fma4(C1, fm1, U[t + 1]);
            }
        }
        r0 = crf_combine<!FINAL>(A0, C0, ucen0, mcen0);
        r1 = crf_combine<!FINAL>(A1, C1, ucen1, mcen1);

        if (FINAL) {
            float* o = dst + ((size_t)b * NCLASS * HH + gh) * WW + gw;
            *reinterpret_cast<float2*>(o)             = make_float2(r0.x, r1.x);
            *reinterpret_cast<float2*>(o + PLANE)     = make_float2(r0.y, r1.y);
            *reinterpret_cast<float2*>(o + 2 * PLANE) = make_float2(r0.z, r1.z);
            *reinterpret_cast<float2*>(o + 3 * PLANE) = make_float2(r0.w, r1.w);
        }
    }

    if (!FINAL) {
        if (in_region) {
            u_dst[lr1 + 1][lc1 + 2] = r0;    // r=0 where global-OOB (zero-pad)
            u_dst[lr1 + 1][lc1 + 3] = r1;
        }
        __syncthreads();   // dst writes visible; src free for reuse next step
    }
}

__global__ __launch_bounds__(512, 4) void crf_fused(
    const float* __restrict__ xin,   // [B,4,H,W]
    const float* __restrict__ filt,  // [B,1,14,H,W]
    const float* __restrict__ mask,  // [B,1,H,W]
    float* __restrict__ xout)        // [B,4,H,W]
{
    __shared__ float4 u0_lds[UR][UC];  // unary ping, 17.0 KB
    __shared__ float4 u1_lds[UR][UC];  // unary pong, 17.0 KB
    __shared__ float  m_lds[UR][UC];   // mask, 4.3 KB

    // ---- XCD-aware swizzle: give each XCD 128 CONSECUTIVE tile-ids (=2 whole
    // batch images), so halo-sharing neighbor tiles co-reside on one L2.
    // Default dispatch round-robins consecutive ids across the 8 XCDs.
    const int bid  = blockIdx.x;                    // 0..1023
    const int xcd  = bid % NXCD;
    const int tile = xcd * (NBLK / NXCD) + bid / NXCD;   // bijective (1024%8==0)
    const int wx   = tile & 7;          // tile % (WW/TW)
    const int hy   = (tile >> 3) & 7;   // (tile/8) % (HH/TH)
    const int b    = tile >> 6;         // tile / 64

    const int h0  = hy * TH;
    const int w0  = wx * TW;
    const int tid = threadIdx.x;

    // ---- phase 0: softmax(x) + mask over the full 14x76 patch, pixel pairs ----
    constexpr int NP = (UR * UC) / 2;   // 532 pairs
    for (int idx = tid; idx < NP; idx += 512) {
        const int lr = idx / (UC / 2);
        const int lc = 2 * (idx - lr * (UC / 2));
        const int ph = h0 + lr - 3;
        const int pw = w0 + lc - 6;     // even -> pair never straddles 0/W
        float4 u0 = make_float4(0.f, 0.f, 0.f, 0.f);
        float4 u1 = u0;
        float2 mm = make_float2(0.f, 0.f);
        if (ph >= 0 && ph < HH && pw >= 0 && pw < WW) {
            const float* px = xin + ((size_t)b * NCLASS * HH + ph) * WW + pw;
            const float2 v0 = *reinterpret_cast<const float2*>(px);
            const float2 v1 = *reinterpret_cast<const float2*>(px + PLANE);
            const float2 v2 = *reinterpret_cast<const float2*>(px + 2 * PLANE);
            const float2 v3 = *reinterpret_cast<const float2*>(px + 3 * PLANE);
            mm = *reinterpret_cast<const float2*>(mask + ((size_t)b * HH + ph) * WW + pw);
            {
                const float mx  = fmaxf(fmaxf(v0.x, v1.x), fmaxf(v2.x, v3.x));
                const float e0  = __expf(v0.x - mx);
                const float e1  = __expf(v1.x - mx);
                const float e2  = __expf(v2.x - mx);
                const float e3  = __expf(v3.x - mx);
                const float inv = 1.0f / (e0 + e1 + e2 + e3);
                u0 = make_float4(e0 * inv, e1 * inv, e2 * inv, e3 * inv);
            }
            {
                const float mx  = fmaxf(fmaxf(v0.y, v1.y), fmaxf(v2.y, v3.y));
                const float e0  = __expf(v0.y - mx);
                const float e1  = __expf(v1.y - mx);
                const float e2  = __expf(v2.y - mx);
                const float e3  = __expf(v3.y - mx);
                const float inv = 1.0f / (e0 + e1 + e2 + e3);
                u1 = make_float4(e0 * inv, e1 * inv, e2 * inv, e3 * inv);
            }
        }
        u0_lds[lr][lc]     = u0;
        u0_lds[lr][lc + 1] = u1;
        *reinterpret_cast<float2*>(&m_lds[lr][lc]) = mm;
    }
    __syncthreads();

    // ---- fixed thread -> pixel-pair mapping over the step-1 region ----
    const int  p     = tid;                    // pair id (0..431 active)
    const int  lr1   = p / GPR1;               // region row
    const int  lc1   = 2 * (p - lr1 * GPR1);   // region col of first pixel (even)
    const int  gh    = h0 + lr1 - 2;
    const int  gw    = w0 + lc1 - 4;
    const bool valid = (p < NPAIR1);
    const bool inb   = valid && gh >= 0 && gh < HH && gw >= 0 && gw < WW;

    // ---- filt taps loaded ONCE (post-barrier; step-1 A-side hides the wait) ----
    float2 f[14];
    if (inb) {
        const float* fp = filt + ((size_t)b * 14 * HH + gh) * WW + gw;
#pragma unroll
        for (int k = 0; k < 14; ++k)
            f[k] = *reinterpret_cast<const float2*>(fp + (size_t)k * PLANE);
    }

    float mcen0 = 0.f, mcen1 = 0.f;
    crf_step<2, 4, true,  false>(u0_lds, u1_lds, m_lds, f, mcen0, mcen1, xout,
                                 b, lr1, lc1, gh, gw, valid, inb);
    crf_step<1, 2, false, false>(u1_lds, u0_lds, m_lds, f, mcen0, mcen1, xout,
                                 b, lr1, lc1, gh, gw, valid, inb);
    crf_step<0, 0, false, true >(u0_lds, u1_lds, m_lds, f, mcen0, mcen1, xout,
                                 b, lr1, lc1, gh, gw, valid, inb);
}

extern "C" void kernel_launch(void* const* d_in, const int* in_sizes, int n_in,
                              void* d_out, int out_size, void* d_ws, size_t ws_size,
                              hipStream_t stream) {
    const float* x    = (const float*)d_in[0];  // [16,4,64,512]
    const float* filt = (const float*)d_in[1];  // [16,1,14,64,512]
    const float* msk  = (const float*)d_in[2];  // [16,1,64,512]
    float* out = (float*)d_out;
    (void)d_ws; (void)ws_size;

    dim3 grid(NBLK);   // 1024 blocks, 1D; tile decomposition + XCD swizzle in-kernel
    dim3 block(512);
    crf_fused<<<grid, block, 0, stream>>>(x, filt, msk, out);
}